// Round 4
// baseline (196.004 us; speedup 1.0000x reference)
//
#include <hip/hip_runtime.h>
#include <hip/hip_bf16.h>

// SimpleOrdinalLinearDecayEmbedding: out[m,d] = gate[m] * (q[m,:]@Wq[d,:]) + bq[d]
// gate[m] = sigmoid(sum_k max(1-|k-r[m]|/3,0)*Wr[k] + br), r in {0..3} -> 4-entry LUT.
// M = B*S = 32768, K = Q = 800, N = D = 64. HBM-bound: 113 MB compulsory traffic,
// floor ~16-18 us. R1->R3 showed access-pattern changes are neutral -> kernel is at
// its BW roofline; dur_us is dominated by harness poison/restore (~160 us fixed).
//
// R4: single kernel, no workspace, no convert launch (one fewer graph node).
// B fragments converted from fp32 Wq in-loop; Wq (205 KB) is L1/L2-resident and the
// extra cvts (~400 VALU cyc/CU/iter vs ~1600 memory cyc) are fully hidden.
// k-slot permutation sigma(lhi,j) = (j<4 ? lhi*4+j : 16+lhi*4+j-4) applied
// identically to A and B (common slot->k map cancels inside the MFMA dot product);
// every A dwordx4 covers full 64B lines (row stride 3200 B = 50 lines, 64B-aligned).

#define QD 800
#define DD 64
#define M_TOTAL 32768
#define KT 25  // 800 / 32

typedef __attribute__((ext_vector_type(8))) short bf16x8;
typedef __attribute__((ext_vector_type(4))) float f32x4;

static __device__ __forceinline__ short f2bf(float f) {
  union { __hip_bfloat16 h; short s; } u;
  u.h = __float2bfloat16(f);
  return u.s;
}

// Load 8 floats for MFMA slots (lhi, j=0..7) with the sigma permutation:
// regs 0..3 <- p[0..3] (= row_base + lhi*4 floats), regs 4..7 <- p[16..19].
static __device__ __forceinline__ bf16x8 load_split8(const float* __restrict__ p) {
  f32x4 lo = *reinterpret_cast<const f32x4*>(p);
  f32x4 hi = *reinterpret_cast<const f32x4*>(p + 16);
  bf16x8 r;
  r[0] = f2bf(lo.x); r[1] = f2bf(lo.y); r[2] = f2bf(lo.z); r[3] = f2bf(lo.w);
  r[4] = f2bf(hi.x); r[5] = f2bf(hi.y); r[6] = f2bf(hi.z); r[7] = f2bf(hi.w);
  return r;
}

// One wave per 16-row M-subtile; 4 accumulators cover all 64 output cols.
// Grid 512 blocks x 4 waves = 2048 waves = 8/CU; unroll-5 keeps ~10 KB of A-loads
// in flight per wave (~80 KB/CU vs ~9 KB needed to cover 900-cyc HBM latency).
__global__ __launch_bounds__(256, 2) void sold_kernel(
    const float* __restrict__ q, const int* __restrict__ rdat,
    const float* __restrict__ Wq, const float* __restrict__ bq,
    const float* __restrict__ Wr, const float* __restrict__ br,
    float* __restrict__ out) {
  const int lane = threadIdx.x & 63;
  const int wave = threadIdx.x >> 6;
  const int l15 = lane & 15;
  const int lhi = lane >> 4;
  const int m0 = blockIdx.x * 64 + wave * 16;

  // A: row = m0 + l15, sigma offset lhi*4 floats (lo) and +16 floats (hi).
  const float* aptr = q + (size_t)(m0 + l15) * QD + lhi * 4;
  // B fragment for acc i, lane: Wq[i*16 + l15][k(lhi,j)] — same sigma as A.
  const float* w0 = Wq + (0 * 16 + l15) * QD + lhi * 4;
  const float* w1 = Wq + (1 * 16 + l15) * QD + lhi * 4;
  const float* w2 = Wq + (2 * 16 + l15) * QD + lhi * 4;
  const float* w3 = Wq + (3 * 16 + l15) * QD + lhi * 4;

  f32x4 acc0 = {0.f, 0.f, 0.f, 0.f};
  f32x4 acc1 = {0.f, 0.f, 0.f, 0.f};
  f32x4 acc2 = {0.f, 0.f, 0.f, 0.f};
  f32x4 acc3 = {0.f, 0.f, 0.f, 0.f};

#pragma unroll 5
  for (int kt = 0; kt < KT; ++kt) {
    bf16x8 a  = load_split8(aptr + kt * 32);
    bf16x8 b0 = load_split8(w0 + kt * 32);
    bf16x8 b1 = load_split8(w1 + kt * 32);
    bf16x8 b2 = load_split8(w2 + kt * 32);
    bf16x8 b3 = load_split8(w3 + kt * 32);
    acc0 = __builtin_amdgcn_mfma_f32_16x16x32_bf16(a, b0, acc0, 0, 0, 0);
    acc1 = __builtin_amdgcn_mfma_f32_16x16x32_bf16(a, b1, acc1, 0, 0, 0);
    acc2 = __builtin_amdgcn_mfma_f32_16x16x32_bf16(a, b2, acc2, 0, 0, 0);
    acc3 = __builtin_amdgcn_mfma_f32_16x16x32_bf16(a, b3, acc3, 0, 0, 0);
  }

  // Gate LUT: r in {0..3}; weights w[k] = max(1-|k-r|/3, 0).
  float wr[4] = {Wr[0], Wr[1], Wr[2], Wr[3]};
  float brv = br[0];
  float lut[4];
  const float inv3 = 1.0f / 3.0f;
#pragma unroll
  for (int r = 0; r < 4; ++r) {
    float s = brv;
#pragma unroll
    for (int k = 0; k < 4; ++k) {
      float w = fmaxf(1.0f - fabsf((float)(k - r)) * inv3, 0.0f);
      s += w * wr[k];
    }
    lut[r] = 1.0f / (1.0f + __expf(-s));
  }

  float bqv0 = bq[0 * 16 + l15];
  float bqv1 = bq[1 * 16 + l15];
  float bqv2 = bq[2 * 16 + l15];
  float bqv3 = bq[3 * 16 + l15];

  // D layout (HW-verified m89): col = lane&15 (+16 per acc), row = (lane>>4)*4 + reg.
#pragma unroll
  for (int r = 0; r < 4; ++r) {
    int row = m0 + lhi * 4 + r;
    float g = lut[rdat[row]];
    float* orow = out + (size_t)row * DD + l15;
    orow[0]  = acc0[r] * g + bqv0;
    orow[16] = acc1[r] * g + bqv1;
    orow[32] = acc2[r] * g + bqv2;
    orow[48] = acc3[r] * g + bqv3;
  }
}

extern "C" void kernel_launch(void* const* d_in, const int* in_sizes, int n_in,
                              void* d_out, int out_size, void* d_ws, size_t ws_size,
                              hipStream_t stream) {
  const float* q    = (const float*)d_in[0];  // [64,512,800] f32
  const int*   rdat = (const int*)d_in[1];    // [64,512] i32
  const float* Wq   = (const float*)d_in[2];  // [64,800] f32
  const float* bq   = (const float*)d_in[3];  // [64] f32
  const float* Wr   = (const float*)d_in[4];  // [1,4] f32
  const float* br   = (const float*)d_in[5];  // [1] f32
  float* out = (float*)d_out;                 // [64,512,64] f32

  sold_kernel<<<M_TOTAL / 64, 256, 0, stream>>>(q, rdat, Wq, bq, Wr, br, out);
}

// Round 5
// 177.053 us; speedup vs baseline: 1.1070x; 1.1070x over previous
//
#include <hip/hip_runtime.h>
#include <hip/hip_bf16.h>

// SimpleOrdinalLinearDecayEmbedding: out[m,d] = gate[m] * (q[m,:]@Wq[d,:]) + bq[d]
// gate[m] = sigmoid(sum_k max(1-|k-r[m]|/3,0)*Wr[k] + br), r in {0..3} -> 4-entry LUT.
// M = B*S = 32768, K = Q = 800, N = D = 64.
//
// R4 counters: sold_kernel 75us, hbm 10% peak, MfmaUtil 1.6%, VALUBusy 3.4%,
// Occupancy 21%, VGPR=32 -> LATENCY-bound: compiler rolled the loop with ~2-3
// outstanding loads/wave and grid caps at 8 waves/CU. R5 attacks MLP both ways:
//  (a) K-split x2: waves 0-1 = kt 0..12, waves 2-3 = kt 13..24 of the same two
//      16-row tiles; fp32 partials combined via 8 KB LDS -> 16 waves/CU.
//  (b) compile-time K-loop counts (template CNT, full unroll) + bf16 B workspace
//      (reverts R4's fp32-B regression) so the compiler hoists loads (m97-style
//      fine-grained vmcnt) instead of serializing at VGPR=32.

#define QD 800
#define DD 64
#define M_TOTAL 32768
#define KT 25      // 800 / 32
#define KSPLIT 13  // waves 0-1: kt 0..12 (13 tiles); waves 2-3: kt 13..24 (12)

typedef __attribute__((ext_vector_type(8))) short bf16x8;
typedef __attribute__((ext_vector_type(4))) float f32x4;

static __device__ __forceinline__ short f2bf(float f) {
  union { __hip_bfloat16 h; short s; } u;
  u.h = __float2bfloat16(f);
  return u.s;
}

static __device__ __forceinline__ bf16x8 pack8(f32x4 lo, f32x4 hi) {
  bf16x8 r;
  r[0] = f2bf(lo.x); r[1] = f2bf(lo.y); r[2] = f2bf(lo.z); r[3] = f2bf(lo.w);
  r[4] = f2bf(hi.x); r[5] = f2bf(hi.y); r[6] = f2bf(hi.z); r[7] = f2bf(hi.w);
  return r;
}

// 8 floats for MFMA slots (lhi, j=0..7), sigma(lhi,j) = (j<4 ? lhi*4+j : 16+lhi*4+j-4):
// regs 0..3 <- p[0..3], regs 4..7 <- p[16..19]; caller passes p = row_base + lhi*4.
static __device__ __forceinline__ bf16x8 load_split8(const float* __restrict__ p) {
  return pack8(*reinterpret_cast<const f32x4*>(p),
               *reinterpret_cast<const f32x4*>(p + 16));
}

// Prep: B blob, chunk idx = (kt*4 + acc)*64 + lane holds the 8 bf16 B-fragment
// values for (kt, acc, lane): Wq[acc*16+(lane&15)][kt*32+sigma]. 100 KB total.
__global__ void convert_wq_kernel(const float* __restrict__ Wq, short* __restrict__ Bb) {
  int idx = blockIdx.x * 256 + threadIdx.x;  // 6400 threads
  int kt = idx >> 8;
  int acc = (idx >> 6) & 3;
  int lane = idx & 63;
  int l15 = lane & 15, lhi = lane >> 4;
  const float* p = Wq + (acc * 16 + l15) * QD + kt * 32 + lhi * 4;
  bf16x8 r = load_split8(p);
  *reinterpret_cast<bf16x8*>(Bb + (size_t)idx * 8) = r;
}

// Fully-unrolled K-loop over CNT 32-wide k-tiles starting at the caller's base.
template <int CNT, bool USE_WS>
static __device__ __forceinline__ void kloop(
    const float* __restrict__ ap, const short* __restrict__ bp,
    const float* __restrict__ w0, const float* __restrict__ w1,
    const float* __restrict__ w2, const float* __restrict__ w3,
    f32x4& acc0, f32x4& acc1, f32x4& acc2, f32x4& acc3) {
#pragma unroll
  for (int i = 0; i < CNT; ++i) {
    bf16x8 a = load_split8(ap + i * 32);
    bf16x8 b0, b1, b2, b3;
    if constexpr (USE_WS) {
      const short* p = bp + i * 2048;
      b0 = *reinterpret_cast<const bf16x8*>(p + 0 * 512);
      b1 = *reinterpret_cast<const bf16x8*>(p + 1 * 512);
      b2 = *reinterpret_cast<const bf16x8*>(p + 2 * 512);
      b3 = *reinterpret_cast<const bf16x8*>(p + 3 * 512);
    } else {
      b0 = load_split8(w0 + i * 32);
      b1 = load_split8(w1 + i * 32);
      b2 = load_split8(w2 + i * 32);
      b3 = load_split8(w3 + i * 32);
    }
    acc0 = __builtin_amdgcn_mfma_f32_16x16x32_bf16(a, b0, acc0, 0, 0, 0);
    acc1 = __builtin_amdgcn_mfma_f32_16x16x32_bf16(a, b1, acc1, 0, 0, 0);
    acc2 = __builtin_amdgcn_mfma_f32_16x16x32_bf16(a, b2, acc2, 0, 0, 0);
    acc3 = __builtin_amdgcn_mfma_f32_16x16x32_bf16(a, b3, acc3, 0, 0, 0);
  }
}

// Block = 4 waves over 32 rows: wave = {tile(0/1), khalf(0/1)}. Each wave computes
// a 16-row x 64-col partial over its K-half; khalf=1 partials combined via LDS.
template <bool USE_WS>
__global__ __launch_bounds__(256, 4) void sold_kernel(
    const float* __restrict__ q, const int* __restrict__ rdat,
    const short* __restrict__ Bb, const float* __restrict__ Wq,
    const float* __restrict__ bq, const float* __restrict__ Wr,
    const float* __restrict__ br, float* __restrict__ out) {
  const int lane = threadIdx.x & 63;
  const int wave = threadIdx.x >> 6;
  const int l15 = lane & 15;
  const int lhi = lane >> 4;
  const int tile = wave & 1;
  const int khalf = wave >> 1;
  const int m0 = blockIdx.x * 32 + tile * 16;
  const int kt0 = khalf ? KSPLIT : 0;

  const float* ap = q + (size_t)(m0 + l15) * QD + kt0 * 32 + lhi * 4;
  const short* bp = Bb + (size_t)kt0 * 2048 + lane * 8;
  const float* w0 = Wq + (0 * 16 + l15) * QD + kt0 * 32 + lhi * 4;
  const float* w1 = Wq + (1 * 16 + l15) * QD + kt0 * 32 + lhi * 4;
  const float* w2 = Wq + (2 * 16 + l15) * QD + kt0 * 32 + lhi * 4;
  const float* w3 = Wq + (3 * 16 + l15) * QD + kt0 * 32 + lhi * 4;

  f32x4 acc0 = {0.f, 0.f, 0.f, 0.f};
  f32x4 acc1 = {0.f, 0.f, 0.f, 0.f};
  f32x4 acc2 = {0.f, 0.f, 0.f, 0.f};
  f32x4 acc3 = {0.f, 0.f, 0.f, 0.f};

  if (khalf == 0) {
    kloop<KSPLIT, USE_WS>(ap, bp, w0, w1, w2, w3, acc0, acc1, acc2, acc3);
  } else {
    kloop<KT - KSPLIT, USE_WS>(ap, bp, w0, w1, w2, w3, acc0, acc1, acc2, acc3);
  }

  // Combine: khalf=1 waves publish partials; khalf=0 waves reduce + epilogue.
  // Layout [tile][j][lane]: lane-stride 4 B -> conflict-free.
  __shared__ float comb[2][16][64];
  if (khalf == 1) {
#pragma unroll
    for (int r = 0; r < 4; ++r) {
      comb[tile][0 * 4 + r][lane] = acc0[r];
      comb[tile][1 * 4 + r][lane] = acc1[r];
      comb[tile][2 * 4 + r][lane] = acc2[r];
      comb[tile][3 * 4 + r][lane] = acc3[r];
    }
  }
  __syncthreads();
  if (khalf == 1) return;

#pragma unroll
  for (int r = 0; r < 4; ++r) {
    acc0[r] += comb[tile][0 * 4 + r][lane];
    acc1[r] += comb[tile][1 * 4 + r][lane];
    acc2[r] += comb[tile][2 * 4 + r][lane];
    acc3[r] += comb[tile][3 * 4 + r][lane];
  }

  // Gate LUT: r in {0..3}; weights w[k] = max(1-|k-r|/3, 0).
  float wr[4] = {Wr[0], Wr[1], Wr[2], Wr[3]};
  float brv = br[0];
  float lut[4];
  const float inv3 = 1.0f / 3.0f;
#pragma unroll
  for (int r = 0; r < 4; ++r) {
    float s = brv;
#pragma unroll
    for (int k = 0; k < 4; ++k) {
      float w = fmaxf(1.0f - fabsf((float)(k - r)) * inv3, 0.0f);
      s += w * wr[k];
    }
    lut[r] = 1.0f / (1.0f + __expf(-s));
  }

  float bqv0 = bq[0 * 16 + l15];
  float bqv1 = bq[1 * 16 + l15];
  float bqv2 = bq[2 * 16 + l15];
  float bqv3 = bq[3 * 16 + l15];

  // D layout (HW-verified m89): col = lane&15 (+16 per acc), row = (lane>>4)*4 + reg.
#pragma unroll
  for (int r = 0; r < 4; ++r) {
    int row = m0 + lhi * 4 + r;
    float g = lut[rdat[row]];
    float* orow = out + (size_t)row * DD + l15;
    orow[0]  = acc0[r] * g + bqv0;
    orow[16] = acc1[r] * g + bqv1;
    orow[32] = acc2[r] * g + bqv2;
    orow[48] = acc3[r] * g + bqv3;
  }
}

extern "C" void kernel_launch(void* const* d_in, const int* in_sizes, int n_in,
                              void* d_out, int out_size, void* d_ws, size_t ws_size,
                              hipStream_t stream) {
  const float* q    = (const float*)d_in[0];  // [64,512,800] f32
  const int*   rdat = (const int*)d_in[1];    // [64,512] i32
  const float* Wq   = (const float*)d_in[2];  // [64,800] f32
  const float* bq   = (const float*)d_in[3];  // [64] f32
  const float* Wr   = (const float*)d_in[4];  // [1,4] f32
  const float* br   = (const float*)d_in[5];  // [1] f32
  float* out = (float*)d_out;                 // [64,512,64] f32

  const size_t need_ws = (size_t)KT * 4 * 64 * 8 * sizeof(short);  // 102400 B
  const int grid = M_TOTAL / 32;  // 1024 blocks x 4 waves = 16 waves/CU
  if (ws_size >= need_ws) {
    short* Bb = (short*)d_ws;
    convert_wq_kernel<<<KT, 256, 0, stream>>>(Wq, Bb);
    sold_kernel<true><<<grid, 256, 0, stream>>>(q, rdat, Bb, Wq, bq, Wr, br, out);
  } else {
    sold_kernel<false><<<grid, 256, 0, stream>>>(q, rdat, nullptr, Wq, bq, Wr, br, out);
  }
}

// Round 6
// 171.342 us; speedup vs baseline: 1.1439x; 1.0333x over previous
//
#include <hip/hip_runtime.h>
#include <hip/hip_bf16.h>
#include <stdint.h>

// SimpleOrdinalLinearDecayEmbedding: out[m,d] = gate[m] * (q[m,:]@Wq[d,:]) + bq[d]
// gate[m] = sigmoid(sum_k max(1-|k-r[m]|/3,0)*Wr[k] + br), r in {0..3} -> LUT.
// M = 32768, K = 800, N = 64.
//
// R5 post-mortem: direct per-wave loads are latency-bound (in-order vmcnt queue,
// VGPR-limited outstanding loads) -> 820 GB/s. R6: m97-style async staging with
// __builtin_amdgcn_global_load_lds (no VGPR cost, deep queue), PIPE=3 LDS ring,
// 1024 blocks x 128 thr (32 rows each) -> 4 blocks/CU, ~96 KB in flight per CU.
// A tile staged with XOR-swizzled ksegs so ds_read_b128 fragment readback has
// canonical (contiguous-equivalent) bank density; B staged from the bf16 blob.

#define QD 800
#define DD 64
#define M_TOTAL 32768
#define KT 25    // 800 / 32
#define PIPE 3

typedef __attribute__((ext_vector_type(8))) short bf16x8;
typedef __attribute__((ext_vector_type(4))) float f32x4;

typedef const __attribute__((address_space(1))) uint32_t* gas1_u32;
typedef __attribute__((address_space(3))) uint32_t* las3_u32;

static __device__ __forceinline__ void gll16(const void* g, const void* l) {
  // dest = wave-uniform LDS base + lane*16 (HW rule, m104/m108): caller passes a
  // wave-uniform l; low 32 bits of the flat shared address are the LDS offset.
  __builtin_amdgcn_global_load_lds((gas1_u32)(uintptr_t)g,
                                   (las3_u32)(uint32_t)(uintptr_t)l, 16, 0, 0);
}

static __device__ __forceinline__ short f2bf(float f) {
  union { __hip_bfloat16 h; short s; } u;
  u.h = __float2bfloat16(f);
  return u.s;
}

static __device__ __forceinline__ bf16x8 pack8(f32x4 lo, f32x4 hi) {
  bf16x8 r;
  r[0] = f2bf(lo.x); r[1] = f2bf(lo.y); r[2] = f2bf(lo.z); r[3] = f2bf(lo.w);
  r[4] = f2bf(hi.x); r[5] = f2bf(hi.y); r[6] = f2bf(hi.z); r[7] = f2bf(hi.w);
  return r;
}

// sigma(lhi,j) = (j<4 ? lhi*4+j : 16+lhi*4+j-4): lo ksegs = lhi, hi ksegs = 4+lhi.
static __device__ __forceinline__ bf16x8 load_split8(const float* __restrict__ p) {
  return pack8(*reinterpret_cast<const f32x4*>(p),
               *reinterpret_cast<const f32x4*>(p + 16));
}

// Prep: B blob. Chunk idx = (kt*4 + acc)*64 + lane holds the 8 bf16 B-fragment
// values for (kt, acc, lane): Wq[acc*16+(lane&15)][kt*32+sigma]. 100 KB.
__global__ void convert_wq_kernel(const float* __restrict__ Wq, short* __restrict__ Bb) {
  int idx = blockIdx.x * 256 + threadIdx.x;  // 6400 threads
  int kt = idx >> 8;
  int acc = (idx >> 6) & 3;
  int lane = idx & 63;
  int l15 = lane & 15, lhi = lane >> 4;
  const float* p = Wq + (acc * 16 + l15) * QD + kt * 32 + lhi * 4;
  *reinterpret_cast<bf16x8*>(Bb + (size_t)idx * 8) = load_split8(p);
}

// Stage one k-tile: A = 32 rows x 32 floats (4 KB, 256 slots), slot s holds
// kseg = (s&7) ^ (row&7), row = s>>3 (XOR swizzle for conflict-free readback);
// B = 4 KB bf16 blob slice, slot s = blob[kt*2048 + s*8], contiguous.
static __device__ __forceinline__ void stage(
    const float* __restrict__ qbase, const short* __restrict__ blob, int kt,
    float* bufA, short* bufB, int t, int wave) {
  const float* qk = qbase + kt * 32;
  const short* bk = blob + (size_t)kt * 2048;
#pragma unroll
  for (int j = 0; j < 2; ++j) {
    int s = j * 128 + t;
    int row = s >> 3;
    int kseg = (s & 7) ^ (row & 7);
    gll16(qk + (size_t)row * QD + kseg * 4, bufA + (j * 128 + wave * 64) * 4);
  }
#pragma unroll
  for (int j = 0; j < 2; ++j) {
    int s = j * 128 + t;
    gll16(bk + s * 8, bufB + (j * 128 + wave * 64) * 8);
  }
}

__global__ __launch_bounds__(128, 2) void sold_kernel(
    const float* __restrict__ q, const int* __restrict__ rdat,
    const short* __restrict__ Bb, const float* __restrict__ bq,
    const float* __restrict__ Wr, const float* __restrict__ br,
    float* __restrict__ out) {
  const int t = threadIdx.x;
  const int lane = t & 63;
  const int wave = t >> 6;          // 0..1, each owns a 16-row subtile
  const int l15 = lane & 15;
  const int lhi = lane >> 4;
  const int m0 = blockIdx.x * 32;

  __shared__ __align__(16) float bufA[PIPE][1024];   // 3 x 4 KB
  __shared__ __align__(16) short bufB[PIPE][2048];   // 3 x 4 KB

  const float* qbase = q + (size_t)m0 * QD;

  f32x4 acc0 = {0.f, 0.f, 0.f, 0.f};
  f32x4 acc1 = {0.f, 0.f, 0.f, 0.f};
  f32x4 acc2 = {0.f, 0.f, 0.f, 0.f};
  f32x4 acc3 = {0.f, 0.f, 0.f, 0.f};

  stage(qbase, Bb, 0, bufA[0], bufB[0], t, wave);
  stage(qbase, Bb, 1, bufA[1], bufB[1], t, wave);

  const int row32 = wave * 16 + l15;
  const int rb = row32 & 7;                 // == l15 & 7
  const int offA_lo = row32 * 32 + ((0 + lhi) ^ rb) * 4;
  const int offA_hi = row32 * 32 + ((4 + lhi) ^ rb) * 4;

  for (int kt = 0; kt < KT; ++kt) {
    __syncthreads();  // drains vmcnt -> slot kt ready; slot (kt-1)%3 free
    int nx = kt + 2;
    int sl = kt % PIPE;
    if (nx < KT) stage(qbase, Bb, nx, bufA[nx % PIPE], bufB[nx % PIPE], t, wave);

    const float* A = bufA[sl];
    const short* B = bufB[sl];
    f32x4 alo = *reinterpret_cast<const f32x4*>(A + offA_lo);
    f32x4 ahi = *reinterpret_cast<const f32x4*>(A + offA_hi);
    bf16x8 a = pack8(alo, ahi);
    bf16x8 b0 = *reinterpret_cast<const bf16x8*>(B + (0 * 64 + lane) * 8);
    bf16x8 b1 = *reinterpret_cast<const bf16x8*>(B + (1 * 64 + lane) * 8);
    bf16x8 b2 = *reinterpret_cast<const bf16x8*>(B + (2 * 64 + lane) * 8);
    bf16x8 b3 = *reinterpret_cast<const bf16x8*>(B + (3 * 64 + lane) * 8);
    acc0 = __builtin_amdgcn_mfma_f32_16x16x32_bf16(a, b0, acc0, 0, 0, 0);
    acc1 = __builtin_amdgcn_mfma_f32_16x16x32_bf16(a, b1, acc1, 0, 0, 0);
    acc2 = __builtin_amdgcn_mfma_f32_16x16x32_bf16(a, b2, acc2, 0, 0, 0);
    acc3 = __builtin_amdgcn_mfma_f32_16x16x32_bf16(a, b3, acc3, 0, 0, 0);
  }

  // Gate LUT: r in {0..3}; weights w[k] = max(1-|k-r|/3, 0).
  float wr[4] = {Wr[0], Wr[1], Wr[2], Wr[3]};
  float brv = br[0];
  float lut[4];
  const float inv3 = 1.0f / 3.0f;
#pragma unroll
  for (int r = 0; r < 4; ++r) {
    float s = brv;
#pragma unroll
    for (int k = 0; k < 4; ++k) {
      float w = fmaxf(1.0f - fabsf((float)(k - r)) * inv3, 0.0f);
      s += w * wr[k];
    }
    lut[r] = 1.0f / (1.0f + __expf(-s));
  }

  float bqv0 = bq[0 * 16 + l15];
  float bqv1 = bq[1 * 16 + l15];
  float bqv2 = bq[2 * 16 + l15];
  float bqv3 = bq[3 * 16 + l15];

  // D layout (HW-verified m89): col = lane&15 (+16 per acc), row = (lane>>4)*4 + reg.
#pragma unroll
  for (int r = 0; r < 4; ++r) {
    int row = m0 + wave * 16 + lhi * 4 + r;
    float g = lut[rdat[row]];
    float* orow = out + (size_t)row * DD + l15;
    orow[0]  = acc0[r] * g + bqv0;
    orow[16] = acc1[r] * g + bqv1;
    orow[32] = acc2[r] * g + bqv2;
    orow[48] = acc3[r] * g + bqv3;
  }
}

// Fallback (ws too small — never expected: harness ws ~410 MB): R4-style direct.
__global__ __launch_bounds__(256, 2) void sold_direct(
    const float* __restrict__ q, const int* __restrict__ rdat,
    const float* __restrict__ Wq, const float* __restrict__ bq,
    const float* __restrict__ Wr, const float* __restrict__ br,
    float* __restrict__ out) {
  const int lane = threadIdx.x & 63;
  const int wave = threadIdx.x >> 6;
  const int l15 = lane & 15;
  const int lhi = lane >> 4;
  const int m0 = blockIdx.x * 64 + wave * 16;
  const float* aptr = q + (size_t)(m0 + l15) * QD + lhi * 4;
  const float* w0 = Wq + (0 * 16 + l15) * QD + lhi * 4;
  const float* w1 = Wq + (1 * 16 + l15) * QD + lhi * 4;
  const float* w2 = Wq + (2 * 16 + l15) * QD + lhi * 4;
  const float* w3 = Wq + (3 * 16 + l15) * QD + lhi * 4;
  f32x4 acc0 = {0.f,0.f,0.f,0.f}, acc1 = {0.f,0.f,0.f,0.f};
  f32x4 acc2 = {0.f,0.f,0.f,0.f}, acc3 = {0.f,0.f,0.f,0.f};
#pragma unroll 5
  for (int kt = 0; kt < KT; ++kt) {
    bf16x8 a  = load_split8(aptr + kt * 32);
    bf16x8 b0 = load_split8(w0 + kt * 32);
    bf16x8 b1 = load_split8(w1 + kt * 32);
    bf16x8 b2 = load_split8(w2 + kt * 32);
    bf16x8 b3 = load_split8(w3 + kt * 32);
    acc0 = __builtin_amdgcn_mfma_f32_16x16x32_bf16(a, b0, acc0, 0, 0, 0);
    acc1 = __builtin_amdgcn_mfma_f32_16x16x32_bf16(a, b1, acc1, 0, 0, 0);
    acc2 = __builtin_amdgcn_mfma_f32_16x16x32_bf16(a, b2, acc2, 0, 0, 0);
    acc3 = __builtin_amdgcn_mfma_f32_16x16x32_bf16(a, b3, acc3, 0, 0, 0);
  }
  float wr[4] = {Wr[0], Wr[1], Wr[2], Wr[3]};
  float brv = br[0], lut[4];
  const float inv3 = 1.0f / 3.0f;
#pragma unroll
  for (int r = 0; r < 4; ++r) {
    float s = brv;
#pragma unroll
    for (int k = 0; k < 4; ++k)
      s += fmaxf(1.0f - fabsf((float)(k - r)) * inv3, 0.0f) * wr[k];
    lut[r] = 1.0f / (1.0f + __expf(-s));
  }
  float bqv0 = bq[l15], bqv1 = bq[16 + l15], bqv2 = bq[32 + l15], bqv3 = bq[48 + l15];
#pragma unroll
  for (int r = 0; r < 4; ++r) {
    int row = m0 + lhi * 4 + r;
    float g = lut[rdat[row]];
    float* orow = out + (size_t)row * DD + l15;
    orow[0]  = acc0[r] * g + bqv0;
    orow[16] = acc1[r] * g + bqv1;
    orow[32] = acc2[r] * g + bqv2;
    orow[48] = acc3[r] * g + bqv3;
  }
}

extern "C" void kernel_launch(void* const* d_in, const int* in_sizes, int n_in,
                              void* d_out, int out_size, void* d_ws, size_t ws_size,
                              hipStream_t stream) {
  const float* q    = (const float*)d_in[0];  // [64,512,800] f32
  const int*   rdat = (const int*)d_in[1];    // [64,512] i32
  const float* Wq   = (const float*)d_in[2];  // [64,800] f32
  const float* bq   = (const float*)d_in[3];  // [64] f32
  const float* Wr   = (const float*)d_in[4];  // [1,4] f32
  const float* br   = (const float*)d_in[5];  // [1] f32
  float* out = (float*)d_out;                 // [64,512,64] f32

  const size_t need_ws = (size_t)KT * 2048 * sizeof(short);  // 102400 B
  if (ws_size >= need_ws) {
    short* Bb = (short*)d_ws;
    convert_wq_kernel<<<KT, 256, 0, stream>>>(Wq, Bb);
    sold_kernel<<<M_TOTAL / 32, 128, 0, stream>>>(q, rdat, Bb, bq, Wr, br, out);
  } else {
    sold_direct<<<M_TOTAL / 64, 256, 0, stream>>>(q, rdat, Wq, bq, Wr, br, out);
  }
}

// Round 7
// 169.760 us; speedup vs baseline: 1.1546x; 1.0093x over previous
//
#include <hip/hip_runtime.h>
#include <hip/hip_bf16.h>

// SimpleOrdinalLinearDecayEmbedding: out[m,d] = gate[m] * (q[m,:]@Wq[d,:]) + bq[d]
// gate[m] = sigmoid(sum_k max(1-|k-r[m]|/3,0)*Wr[k] + br), r in {0..3} -> LUT.
// M = 32768, K = 800, N = 64.
//
// R6 post-mortem: __syncthreads drains vmcnt(0) incl. the just-issued prefetch ->
// the LDS ring degenerates to synchronous staging (~48us). R4's VGPR=32 proved the
// scheduler sinks loads next to uses, so plain unrolling builds no prefetch depth.
//
// R7: register-resident software pipeline, no LDS, no barriers. DEPTH=5 explicit
// stage arrays (KT=25=5x5), loads for kt+5 issued at iter kt, and
// __builtin_amdgcn_sched_barrier(0) at each unrolled-iter boundary pins the
// schedule so loads keep >=4 compute-blocks of distance. VGPR loads get exact
// automatic s_waitcnt vmcnt(N). ~24 KB in flight/wave x 8 waves/CU >> BW*latency.

#define QD 800
#define DD 64
#define M_TOTAL 32768
#define KT 25     // 800 / 32
#define DEPTH 5   // pipeline stages; 25 % 5 == 0

typedef __attribute__((ext_vector_type(8))) short bf16x8;
typedef __attribute__((ext_vector_type(4))) float f32x4;

static __device__ __forceinline__ short f2bf(float f) {
  union { __hip_bfloat16 h; short s; } u;
  u.h = __float2bfloat16(f);
  return u.s;
}

static __device__ __forceinline__ bf16x8 pack8(f32x4 lo, f32x4 hi) {
  bf16x8 r;
  r[0] = f2bf(lo.x); r[1] = f2bf(lo.y); r[2] = f2bf(lo.z); r[3] = f2bf(lo.w);
  r[4] = f2bf(hi.x); r[5] = f2bf(hi.y); r[6] = f2bf(hi.z); r[7] = f2bf(hi.w);
  return r;
}

// sigma(lhi,j) = (j<4 ? lhi*4+j : 16+lhi*4+j-4): lo ksegs at +0, hi at +16 floats.
static __device__ __forceinline__ bf16x8 load_split8(const float* __restrict__ p) {
  return pack8(*reinterpret_cast<const f32x4*>(p),
               *reinterpret_cast<const f32x4*>(p + 16));
}

// Prep: B blob. Chunk idx = (kt*4 + acc)*64 + lane holds the 8 bf16 B-fragment
// values for (kt, acc, lane): Wq[acc*16+(lane&15)][kt*32+sigma]. 100 KB, L2-hot.
__global__ void convert_wq_kernel(const float* __restrict__ Wq, short* __restrict__ Bb) {
  int idx = blockIdx.x * 256 + threadIdx.x;  // 6400 threads
  int kt = idx >> 8;
  int acc = (idx >> 6) & 3;
  int lane = idx & 63;
  int l15 = lane & 15, lhi = lane >> 4;
  const float* p = Wq + (acc * 16 + l15) * QD + kt * 32 + lhi * 4;
  *reinterpret_cast<bf16x8*>(Bb + (size_t)idx * 8) = load_split8(p);
}

// 512 blocks x 4 independent waves (16 rows each, no barriers) = 8 waves/CU.
__global__ __launch_bounds__(256, 2) void sold_kernel(
    const float* __restrict__ q, const int* __restrict__ rdat,
    const short* __restrict__ Bb, const float* __restrict__ bq,
    const float* __restrict__ Wr, const float* __restrict__ br,
    float* __restrict__ out) {
  const int lane = threadIdx.x & 63;
  const int wave = threadIdx.x >> 6;
  const int l15 = lane & 15;
  const int lhi = lane >> 4;
  const int m0 = blockIdx.x * 64 + wave * 16;

  const float* ap = q + (size_t)(m0 + l15) * QD + lhi * 4;  // + kt*32
  const short* bp = Bb + (size_t)lane * 8;                  // + kt*2048 + acc*512

  // Pipeline registers: 5 stages x (A: 8 f32 = 8 VGPR, B: 4 x bf16x8 = 16 VGPR).
  f32x4 aLo[DEPTH], aHi[DEPTH];
  bf16x8 bfr[DEPTH][4];

#pragma unroll
  for (int s = 0; s < DEPTH; ++s) {
    const float* a = ap + s * 32;
    aLo[s] = *reinterpret_cast<const f32x4*>(a);
    aHi[s] = *reinterpret_cast<const f32x4*>(a + 16);
    const short* p = bp + s * 2048;
    bfr[s][0] = *reinterpret_cast<const bf16x8*>(p + 0 * 512);
    bfr[s][1] = *reinterpret_cast<const bf16x8*>(p + 1 * 512);
    bfr[s][2] = *reinterpret_cast<const bf16x8*>(p + 2 * 512);
    bfr[s][3] = *reinterpret_cast<const bf16x8*>(p + 3 * 512);
  }

  f32x4 acc0 = {0.f, 0.f, 0.f, 0.f};
  f32x4 acc1 = {0.f, 0.f, 0.f, 0.f};
  f32x4 acc2 = {0.f, 0.f, 0.f, 0.f};
  f32x4 acc3 = {0.f, 0.f, 0.f, 0.f};

#pragma unroll
  for (int kt = 0; kt < KT; ++kt) {
    const int s = kt % DEPTH;
    // Compute tile kt from stage s (loads issued 5 iters ago -> auto vmcnt(N)).
    bf16x8 a = pack8(aLo[s], aHi[s]);
    acc0 = __builtin_amdgcn_mfma_f32_16x16x32_bf16(a, bfr[s][0], acc0, 0, 0, 0);
    acc1 = __builtin_amdgcn_mfma_f32_16x16x32_bf16(a, bfr[s][1], acc1, 0, 0, 0);
    acc2 = __builtin_amdgcn_mfma_f32_16x16x32_bf16(a, bfr[s][2], acc2, 0, 0, 0);
    acc3 = __builtin_amdgcn_mfma_f32_16x16x32_bf16(a, bfr[s][3], acc3, 0, 0, 0);
    // Refill stage s with tile kt+5.
    const int nx = kt + DEPTH;
    if (nx < KT) {
      const float* a2 = ap + nx * 32;
      aLo[s] = *reinterpret_cast<const f32x4*>(a2);
      aHi[s] = *reinterpret_cast<const f32x4*>(a2 + 16);
      const short* p = bp + nx * 2048;
      bfr[s][0] = *reinterpret_cast<const bf16x8*>(p + 0 * 512);
      bfr[s][1] = *reinterpret_cast<const bf16x8*>(p + 1 * 512);
      bfr[s][2] = *reinterpret_cast<const bf16x8*>(p + 2 * 512);
      bfr[s][3] = *reinterpret_cast<const bf16x8*>(p + 3 * 512);
    }
    // Pin the modulo schedule: nothing crosses an iteration boundary, so refills
    // keep >= 4 compute-blocks of distance from their use.
    __builtin_amdgcn_sched_barrier(0);
  }

  // Gate LUT: r in {0..3}; weights w[k] = max(1-|k-r|/3, 0).
  float wr[4] = {Wr[0], Wr[1], Wr[2], Wr[3]};
  float brv = br[0];
  float lut[4];
  const float inv3 = 1.0f / 3.0f;
#pragma unroll
  for (int r = 0; r < 4; ++r) {
    float s = brv;
#pragma unroll
    for (int k = 0; k < 4; ++k) {
      float w = fmaxf(1.0f - fabsf((float)(k - r)) * inv3, 0.0f);
      s += w * wr[k];
    }
    lut[r] = 1.0f / (1.0f + __expf(-s));
  }

  float bqv0 = bq[0 * 16 + l15];
  float bqv1 = bq[1 * 16 + l15];
  float bqv2 = bq[2 * 16 + l15];
  float bqv3 = bq[3 * 16 + l15];

  // D layout (HW-verified m89): col = lane&15 (+16 per acc), row = (lane>>4)*4 + reg.
#pragma unroll
  for (int r = 0; r < 4; ++r) {
    int row = m0 + lhi * 4 + r;
    float g = lut[rdat[row]];
    float* orow = out + (size_t)row * DD + l15;
    orow[0]  = acc0[r] * g + bqv0;
    orow[16] = acc1[r] * g + bqv1;
    orow[32] = acc2[r] * g + bqv2;
    orow[48] = acc3[r] * g + bqv3;
  }
}

// Fallback (ws too small — not expected): R4-style direct from fp32 Wq.
__global__ __launch_bounds__(256, 2) void sold_direct(
    const float* __restrict__ q, const int* __restrict__ rdat,
    const float* __restrict__ Wq, const float* __restrict__ bq,
    const float* __restrict__ Wr, const float* __restrict__ br,
    float* __restrict__ out) {
  const int lane = threadIdx.x & 63;
  const int wave = threadIdx.x >> 6;
  const int l15 = lane & 15;
  const int lhi = lane >> 4;
  const int m0 = blockIdx.x * 64 + wave * 16;
  const float* aptr = q + (size_t)(m0 + l15) * QD + lhi * 4;
  const float* w0 = Wq + (0 * 16 + l15) * QD + lhi * 4;
  const float* w1 = Wq + (1 * 16 + l15) * QD + lhi * 4;
  const float* w2 = Wq + (2 * 16 + l15) * QD + lhi * 4;
  const float* w3 = Wq + (3 * 16 + l15) * QD + lhi * 4;
  f32x4 acc0 = {0.f,0.f,0.f,0.f}, acc1 = {0.f,0.f,0.f,0.f};
  f32x4 acc2 = {0.f,0.f,0.f,0.f}, acc3 = {0.f,0.f,0.f,0.f};
#pragma unroll 5
  for (int kt = 0; kt < KT; ++kt) {
    bf16x8 a  = load_split8(aptr + kt * 32);
    bf16x8 b0 = load_split8(w0 + kt * 32);
    bf16x8 b1 = load_split8(w1 + kt * 32);
    bf16x8 b2 = load_split8(w2 + kt * 32);
    bf16x8 b3 = load_split8(w3 + kt * 32);
    acc0 = __builtin_amdgcn_mfma_f32_16x16x32_bf16(a, b0, acc0, 0, 0, 0);
    acc1 = __builtin_amdgcn_mfma_f32_16x16x32_bf16(a, b1, acc1, 0, 0, 0);
    acc2 = __builtin_amdgcn_mfma_f32_16x16x32_bf16(a, b2, acc2, 0, 0, 0);
    acc3 = __builtin_amdgcn_mfma_f32_16x16x32_bf16(a, b3, acc3, 0, 0, 0);
  }
  float wr[4] = {Wr[0], Wr[1], Wr[2], Wr[3]};
  float brv = br[0], lut[4];
  const float inv3 = 1.0f / 3.0f;
#pragma unroll
  for (int r = 0; r < 4; ++r) {
    float s = brv;
#pragma unroll
    for (int k = 0; k < 4; ++k)
      s += fmaxf(1.0f - fabsf((float)(k - r)) * inv3, 0.0f) * wr[k];
    lut[r] = 1.0f / (1.0f + __expf(-s));
  }
  float bqv0 = bq[l15], bqv1 = bq[16 + l15], bqv2 = bq[32 + l15], bqv3 = bq[48 + l15];
#pragma unroll
  for (int r = 0; r < 4; ++r) {
    int row = m0 + lhi * 4 + r;
    float g = lut[rdat[row]];
    float* orow = out + (size_t)row * DD + l15;
    orow[0]  = acc0[r] * g + bqv0;
    orow[16] = acc1[r] * g + bqv1;
    orow[32] = acc2[r] * g + bqv2;
    orow[48] = acc3[r] * g + bqv3;
  }
}

extern "C" void kernel_launch(void* const* d_in, const int* in_sizes, int n_in,
                              void* d_out, int out_size, void* d_ws, size_t ws_size,
                              hipStream_t stream) {
  const float* q    = (const float*)d_in[0];  // [64,512,800] f32
  const int*   rdat = (const int*)d_in[1];    // [64,512] i32
  const float* Wq   = (const float*)d_in[2];  // [64,800] f32
  const float* bq   = (const float*)d_in[3];  // [64] f32
  const float* Wr   = (const float*)d_in[4];  // [1,4] f32
  const float* br   = (const float*)d_in[5];  // [1] f32
  float* out = (float*)d_out;                 // [64,512,64] f32

  const size_t need_ws = (size_t)KT * 2048 * sizeof(short);  // 102400 B
  if (ws_size >= need_ws) {
    short* Bb = (short*)d_ws;
    convert_wq_kernel<<<KT, 256, 0, stream>>>(Wq, Bb);
    sold_kernel<<<M_TOTAL / 64, 256, 0, stream>>>(q, rdat, Bb, bq, Wr, br, out);
  } else {
    sold_direct<<<M_TOTAL / 64, 256, 0, stream>>>(q, rdat, Wq, bq, Wr, br, out);
  }
}